// Round 2
// baseline (172.093 us; speedup 1.0000x reference)
//
#include <hip/hip_runtime.h>

typedef unsigned short u16;
typedef unsigned int   u32;

typedef __attribute__((ext_vector_type(8))) short short8;
typedef __attribute__((ext_vector_type(4))) float floatx4;
typedef __attribute__((ext_vector_type(2))) float v2f;

// ---- f32 -> bf16 (RNE) ----
__device__ __forceinline__ u16 f2bf(float f) {
    u32 u = __float_as_uint(f);
    u = u + 0x7fffu + ((u >> 16) & 1u);
    return (u16)(u >> 16);
}

// pack two f32 -> two bf16 (round-to-nearest-away) in one v_perm
__device__ __forceinline__ u32 pack2bf(float s0, float s1) {
    u32 a = __float_as_uint(s0) + 0x8000u;
    u32 b = __float_as_uint(s1) + 0x8000u;
    return __builtin_amdgcn_perm(b, a, 0x07060302u);  // {b.hi16, a.hi16}
}

__device__ __forceinline__ floatx4 mfma16(short8 a, short8 b, floatx4 c) {
    return __builtin_amdgcn_mfma_f32_16x16x32_bf16(a, b, c, 0, 0, 0);
}

// ---- prep: build per-thread B-fragment streams.
// W1frag (k_h1, 512-thr): [kt*8192 + t*16 + j*8 + ji] = bf16(W1[(7+kt*32+lq*8+ji)*256 + w*32+j*16+lr])
// W2frag (k_tail p1, 256-thr): [kt*8192 + t*32 + jj*8 + ji] = bf16(W2[(kt*32+lq*8+ji)*256 + wv*64+jj*16+lr])
// W3frag (k_tail p2, 256-thr): [kt*4096 + t*16 + j*8 + ji]  = bf16(W3[(kt*32+lq*8+ji)*128 + wv*32+j*16+lr])
__global__ void k_prep(const float* __restrict__ W1, const float* __restrict__ W2,
                       const float* __restrict__ W3, u16* __restrict__ W1frag,
                       u16* __restrict__ W2frag, u16* __restrict__ W3frag) {
    int idx = blockIdx.x * 256 + threadIdx.x;
    if (idx < 524288) {
        int kt = idx >> 13, r = idx & 8191;
        int t = r >> 4, j = (r >> 3) & 1, ji = r & 7;
        int lane = t & 63, w = t >> 6, lr = lane & 15, lq = lane >> 4;
        W1frag[idx] = f2bf(W1[(7 + kt * 32 + lq * 8 + ji) * 256 + w * 32 + j * 16 + lr]);
    } else if (idx < 589824) {
        int i = idx - 524288;
        int kt = i >> 13, r = i & 8191;
        int t = r >> 5, jj = (r >> 3) & 3, ji = r & 7;
        int lane = t & 63, wv = t >> 6, lr = lane & 15, lq = lane >> 4;
        W2frag[i] = f2bf(W2[(kt * 32 + lq * 8 + ji) * 256 + wv * 64 + jj * 16 + lr]);
    } else if (idx < 622592) {
        int i = idx - 589824;
        int kt = i >> 12, r = i & 4095;
        int t = r >> 4, j = (r >> 3) & 1, ji = r & 7;
        int lane = t & 63, wv = t >> 6, lr = lane & 15, lq = lane >> 4;
        W3frag[i] = f2bf(W3[(kt * 32 + lq * 8 + ji) * 128 + wv * 32 + j * 16 + lr]);
    }
}

// ---- kernel 1: h1 = lrelu( [u,norm,proj,dots] @ W1 + b1 )
// 512 threads (8 waves), M=64 x N=256 per block; wave w owns cols w*32..+32.
// Superstep = K=64 (2 MFMA k-tiles) per barrier; 32 barriers total.
// As dots tile: [2][64][64] bf16, row = 128 B = 8x 16B slots, physical slot =
// data slot ^ (row&7). Both ds_write_b128 (wave w writes slot w of row lane)
// and ds_read_b128 (slot (4kk+lq)^(lr&7)) are conflict-free per half-wave:
// 8 start banks (all mult of 4, covering all 32) x 4 lanes x 4 words = 4/bank.
__global__ __launch_bounds__(512, 4) void k_h1(
    const float* __restrict__ x, const float* __restrict__ u,
    const float* __restrict__ basis, const float* __restrict__ W1,
    const float* __restrict__ b1, const u16* __restrict__ W1frag,
    u16* __restrict__ h1) {
    __shared__ float xls[6144];       // SoA: X[0..2048) Y[2048..4096) Z[4096..6144)
    __shared__ u16 As[2][64][64];     // 16 KB double-buffered dots tile (swizzled)
    __shared__ float rowsml[64][6];
    __shared__ float colsml[256][6];

    const int t = threadIdx.x;
    const int b = blockIdx.y;
    const int i0 = blockIdx.x * 64;
    const int lane = t & 63, w = t >> 6;
    const int lr = lane & 15, lq = lane >> 4;

    // build SoA copy of x[b] (coalesced read, scalar LDS scatter; one-time)
    {
        const float4* src = (const float4*)(x + b * 6144);
#pragma unroll
        for (int kk = 0; kk < 3; ++kk) {
            int q = t + kk * 512;
            float4 v = src[q];
            float vv[4] = {v.x, v.y, v.z, v.w};
            int e = q * 4;
#pragma unroll
            for (int cc = 0; cc < 4; ++cc) {
                int ee = e + cc;
                xls[(ee % 3) * 2048 + ee / 3] = vv[cc];
            }
        }
    }
    if (t < 256) {
        int c = t;
        float u0 = u[b * 2 + 0], u1 = u[b * 2 + 1];
        colsml[c][0] = b1[c] + u0 * W1[c] + u1 * W1[256 + c];
        colsml[c][1] = W1[512 + c];
        colsml[c][2] = W1[768 + c];
        colsml[c][3] = W1[1024 + c];
        colsml[c][4] = W1[1280 + c];
        colsml[c][5] = W1[1536 + c];
    }
    __syncthreads();
    if (t < 64) {
        float xx = xls[i0 + t], xy = xls[2048 + i0 + t], xz = xls[4096 + i0 + t];
        rowsml[t][0] = sqrtf(xx * xx + xy * xy + xz * xz);
#pragma unroll
        for (int p = 0; p < 4; ++p) {
            const float* bp = basis + (b * 4 + p) * 3;
            rowsml[t][1 + p] = xx * bp[0] + xy * bp[1] + xz * bp[2];
        }
    }
    const float ax = xls[i0 + lane];
    const float ay = xls[2048 + i0 + lane];
    const float az = xls[4096 + i0 + lane];
    const u16* wf = W1frag + t * 16;
    const float4* X4 = (const float4*)xls;  // [0..512) X, [512..1024) Y, [1024..1536) Z

    // swizzled LDS addressing (all loop-invariant)
    char* Asb = (char*)As;
    char* aswp = Asb + lane * 128 + ((w ^ (lane & 7)) << 4);   // write ptr, buf0
    int ro[4];
    {
        int s0 = (lq ^ (lr & 7));
#pragma unroll
        for (int i = 0; i < 4; ++i)
            ro[i] = (i * 16 + lr) * 128 + (s0 << 4);           // kk=0; kk=1 is ^64
    }

    // generate 8 dots (cols s*64 + w*8 ..+8) for superstep s into As[buf]
    auto gen_store = [&](int s, int buf) {
        int q = s * 16 + w * 2;                   // wave-uniform -> LDS broadcast
        float4 xv0 = X4[q],        xv1 = X4[q + 1];
        float4 yv0 = X4[512 + q],  yv1 = X4[513 + q];
        float4 zv0 = X4[1024 + q], zv1 = X4[1025 + q];
        v2f xA = {xv0.x, xv0.y}, xB = {xv0.z, xv0.w};
        v2f xC = {xv1.x, xv1.y}, xD = {xv1.z, xv1.w};
        v2f yA = {yv0.x, yv0.y}, yB = {yv0.z, yv0.w};
        v2f yC = {yv1.x, yv1.y}, yD = {yv1.z, yv1.w};
        v2f zA = {zv0.x, zv0.y}, zB = {zv0.z, zv0.w};
        v2f zC = {zv1.x, zv1.y}, zD = {zv1.z, zv1.w};
        v2f dA = xA * ax, dB = xB * ax, dC = xC * ax, dD = xD * ax;
        dA += yA * ay; dB += yB * ay; dC += yC * ay; dD += yD * ay;
        dA += zA * az; dB += zB * az; dC += zC * az; dD += zD * az;
        float s0 = __builtin_amdgcn_sqrtf(dA.x);
        float s1 = __builtin_amdgcn_sqrtf(dA.y);
        float s2 = __builtin_amdgcn_sqrtf(dB.x);
        float s3 = __builtin_amdgcn_sqrtf(dB.y);
        float s4 = __builtin_amdgcn_sqrtf(dC.x);
        float s5 = __builtin_amdgcn_sqrtf(dC.y);
        float s6 = __builtin_amdgcn_sqrtf(dD.x);
        float s7 = __builtin_amdgcn_sqrtf(dD.y);
        uint4 dv;
        dv.x = pack2bf(s0, s1); dv.y = pack2bf(s2, s3);
        dv.z = pack2bf(s4, s5); dv.w = pack2bf(s6, s7);
        *(uint4*)(aswp + buf * 8192) = dv;
    };

    // load 8 A-frags (kk=0: dst[0..4), kk=1: dst[4..8)) for superstep in buf
    auto load_frags = [&](int buf, short8* dst) {
#pragma unroll
        for (int i = 0; i < 4; ++i) {
            dst[i]     = *(const short8*)(Asb + buf * 8192 + ro[i]);
            dst[4 + i] = *(const short8*)(Asb + buf * 8192 + (ro[i] ^ 64));
        }
    };

    floatx4 acc[4][2];
    const floatx4 zero = {0.f, 0.f, 0.f, 0.f};
#pragma unroll
    for (int i = 0; i < 4; ++i)
#pragma unroll
        for (int j = 0; j < 2; ++j) acc[i][j] = zero;

    short8 acur[8], bcur[4], bnxt[4];
    gen_store(0, 0);
#pragma unroll
    for (int kk = 0; kk < 2; ++kk)
#pragma unroll
        for (int j = 0; j < 2; ++j)
            bcur[kk * 2 + j] = *(const short8*)(wf + kk * 8192 + j * 8);
    __syncthreads();
    load_frags(0, acur);

#pragma unroll 2
    for (int s = 0; s < 32; ++s) {
        if (s < 31) {
            const u16* wn = wf + (2 * (s + 1)) * 8192;  // 64B/thread, L2-hot
#pragma unroll
            for (int kk = 0; kk < 2; ++kk)
#pragma unroll
                for (int j = 0; j < 2; ++j)
                    bnxt[kk * 2 + j] = *(const short8*)(wn + kk * 8192 + j * 8);
            gen_store(s + 1, (s + 1) & 1);
        }
#pragma unroll
        for (int kk = 0; kk < 2; ++kk)
#pragma unroll
            for (int i = 0; i < 4; ++i)
#pragma unroll
                for (int j = 0; j < 2; ++j)
                    acc[i][j] = mfma16(acur[kk * 4 + i], bcur[kk * 2 + j], acc[i][j]);
        __syncthreads();
        if (s < 31) {
            load_frags((s + 1) & 1, acur);
#pragma unroll
            for (int j = 0; j < 4; ++j) bcur[j] = bnxt[j];
        }
    }

    // epilogue: small features + bias, LeakyReLU, store bf16
    const int c0 = w * 32 + lr, c1 = c0 + 16;
    float c0v[6], c1v[6];
#pragma unroll
    for (int q = 0; q < 6; ++q) { c0v[q] = colsml[c0][q]; c1v[q] = colsml[c1][q]; }
#pragma unroll
    for (int i = 0; i < 4; ++i) {
#pragma unroll
        for (int r = 0; r < 4; ++r) {
            int row = i * 16 + lq * 4 + r;
            float nrm = rowsml[row][0];
            float p0 = rowsml[row][1], p1 = rowsml[row][2];
            float p2 = rowsml[row][3], p3 = rowsml[row][4];
            u16* orow = h1 + (b * 2048 + i0 + row) * 256;
            float v0 = acc[i][0][r] + c0v[0] + nrm * c0v[1] +
                       p0 * c0v[2] + p1 * c0v[3] + p2 * c0v[4] + p3 * c0v[5];
            v0 = v0 > 0.f ? v0 : 0.01f * v0;
            orow[c0] = f2bf(v0);
            float v1 = acc[i][1][r] + c1v[0] + nrm * c1v[1] +
                       p0 * c1v[2] + p1 * c1v[3] + p2 * c1v[4] + p3 * c1v[5];
            v1 = v1 > 0.f ? v1 : 0.01f * v1;
            orow[c1] = f2bf(v1);
        }
    }
}

// ---- fused tail: h2 = lrelu(h1@W2+b2) (regs->LDS), fk = h2@W3+b3, x-reduce.
// Phase 1 is barrier-free: A-frags direct from global h1, B-frags from W2frag stream.
// Final reduce: scaled by 1/2048 (exact pow2) and atomicAdd straight into out.
__global__ __launch_bounds__(256, 2) void k_tail(
    const u16* __restrict__ h1, const u16* __restrict__ W2frag,
    const float* __restrict__ b2, const u16* __restrict__ W3frag,
    const float* __restrict__ b3, const float* __restrict__ x,
    float* __restrict__ out) {
    __shared__ u16 h2s[64][264];    // 33.8 KB
    __shared__ float colb2[256];
    __shared__ float colb3[128];
    __shared__ float xs[64][4];
    __shared__ float red[128][4];

    const int t = threadIdx.x;
    const int m0 = blockIdx.x * 64;
    const int b = m0 >> 11, i0 = m0 & 2047;
    const int lane = t & 63, wv = t >> 6;
    const int lr = lane & 15, lq = lane >> 4;

    colb2[t] = b2[t];
    if (t < 128) colb3[t] = b3[t];
    if (t < 64) {
        const float* xp = x + (b * 2048 + i0 + t) * 3;
        xs[t][0] = xp[0]; xs[t][1] = xp[1]; xs[t][2] = xp[2];
    }

    // ---- phase 1: h2 tile (no barriers, no LDS staging)
    floatx4 acc[4][4];
    const floatx4 zero = {0.f, 0.f, 0.f, 0.f};
#pragma unroll
    for (int i = 0; i < 4; ++i)
#pragma unroll
        for (int j = 0; j < 4; ++j) acc[i][j] = zero;

    const u16* hsrc = h1 + m0 * 256 + lr * 256 + lq * 8;
    const u16* w2s = W2frag + t * 32;
#pragma unroll 2
    for (int kt = 0; kt < 8; ++kt) {
        short8 af[4], bf[4];
#pragma unroll
        for (int i = 0; i < 4; ++i)
            af[i] = *(const short8*)(hsrc + i * 4096 + kt * 32);
#pragma unroll
        for (int j = 0; j < 4; ++j)
            bf[j] = *(const short8*)(w2s + kt * 8192 + j * 8);
#pragma unroll
        for (int i = 0; i < 4; ++i)
#pragma unroll
            for (int j = 0; j < 4; ++j) acc[i][j] = mfma16(af[i], bf[j], acc[i][j]);
    }
#pragma unroll
    for (int i = 0; i < 4; ++i)
#pragma unroll
        for (int r = 0; r < 4; ++r) {
            int row = i * 16 + lq * 4 + r;
#pragma unroll
            for (int j = 0; j < 4; ++j) {
                int col = wv * 64 + j * 16 + lr;
                float v = acc[i][j][r] + colb2[col];
                v = v > 0.f ? v : 0.01f * v;
                h2s[row][col] = f2bf(v);
            }
        }
    __syncthreads();

    // ---- phase 2: fk = h2s @ W3 + b3 (B from W3frag stream), fused x-reduce
    floatx4 acc2[4][2];
#pragma unroll
    for (int i = 0; i < 4; ++i)
#pragma unroll
        for (int j = 0; j < 2; ++j) acc2[i][j] = zero;

    const u16* w3s = W3frag + t * 16;
#pragma unroll 2
    for (int kt = 0; kt < 8; ++kt) {
        short8 af[4], bf[2];
#pragma unroll
        for (int i = 0; i < 4; ++i)
            af[i] = *(const short8*)&h2s[i * 16 + lr][kt * 32 + lq * 8];
#pragma unroll
        for (int j = 0; j < 2; ++j)
            bf[j] = *(const short8*)(w3s + kt * 4096 + j * 8);
#pragma unroll
        for (int i = 0; i < 4; ++i)
#pragma unroll
            for (int j = 0; j < 2; ++j) acc2[i][j] = mfma16(af[i], bf[j], acc2[i][j]);
    }

    float s[2][3];
#pragma unroll
    for (int j = 0; j < 2; ++j) { s[j][0] = 0.f; s[j][1] = 0.f; s[j][2] = 0.f; }
#pragma unroll
    for (int i = 0; i < 4; ++i)
#pragma unroll
        for (int r = 0; r < 4; ++r) {
            int row = i * 16 + lq * 4 + r;
            float x0 = xs[row][0], x1 = xs[row][1], x2 = xs[row][2];
#pragma unroll
            for (int j = 0; j < 2; ++j) {
                int col = wv * 32 + j * 16 + lr;
                float fk = acc2[i][j][r] + colb3[col];
                s[j][0] += fk * x0; s[j][1] += fk * x1; s[j][2] += fk * x2;
            }
        }
#pragma unroll
    for (int j = 0; j < 2; ++j)
#pragma unroll
        for (int d = 0; d < 3; ++d) {
            float v = s[j][d];
            v += __shfl_xor(v, 16);
            v += __shfl_xor(v, 32);
            if (lane < 16) red[wv * 32 + j * 16 + lane][d] = v;  // wave-exclusive cols
        }
    __syncthreads();
    if (t < 128) {
#pragma unroll
        for (int d = 0; d < 3; ++d)
            atomicAdd(&out[(b * 128 + t) * 3 + d], red[t][d] * (1.0f / 2048.0f));
    }
}

extern "C" void kernel_launch(void* const* d_in, const int* in_sizes, int n_in,
                              void* d_out, int out_size, void* d_ws, size_t ws_size,
                              hipStream_t stream) {
    const float* x     = (const float*)d_in[0];
    const float* u     = (const float*)d_in[1];
    const float* basis = (const float*)d_in[2];
    const float* W1    = (const float*)d_in[3];
    const float* b1    = (const float*)d_in[4];
    const float* W2    = (const float*)d_in[5];
    const float* b2    = (const float*)d_in[6];
    const float* W3    = (const float*)d_in[7];
    const float* b3    = (const float*)d_in[8];
    float* out = (float*)d_out;

    char* ws = (char*)d_ws;
    u16*  W1frag = (u16*)ws;                      // 1,048,576 B
    u16*  W2frag = (u16*)(ws + 1048576);          //   131,072 B
    u16*  W3frag = (u16*)(ws + 1179648);          //    65,536 B
    u16*  h1     = (u16*)(ws + 1245184);          // 16,777,216 B

    hipMemsetAsync(out, 0, 24576, stream);
    k_prep<<<2432, 256, 0, stream>>>(W1, W2, W3, W1frag, W2frag, W3frag);
    k_h1<<<dim3(32, 16), 512, 0, stream>>>(x, u, basis, W1, b1, W1frag, h1);
    k_tail<<<512, 256, 0, stream>>>(h1, W2frag, b2, W3frag, b3, x, out);
}

// Round 3
// 137.650 us; speedup vs baseline: 1.2502x; 1.2502x over previous
//
#include <hip/hip_runtime.h>

typedef unsigned short u16;
typedef unsigned int   u32;

typedef __attribute__((ext_vector_type(8))) short short8;
typedef __attribute__((ext_vector_type(4))) float floatx4;
typedef __attribute__((ext_vector_type(2))) float v2f;

// ---- f32 -> bf16 (RNE) ----
__device__ __forceinline__ u16 f2bf(float f) {
    u32 u = __float_as_uint(f);
    u = u + 0x7fffu + ((u >> 16) & 1u);
    return (u16)(u >> 16);
}

// pack two f32 -> two bf16 (round-to-nearest-away) in one v_perm
__device__ __forceinline__ u32 pack2bf(float s0, float s1) {
    u32 a = __float_as_uint(s0) + 0x8000u;
    u32 b = __float_as_uint(s1) + 0x8000u;
    return __builtin_amdgcn_perm(b, a, 0x07060302u);  // {b.hi16, a.hi16}
}

__device__ __forceinline__ floatx4 mfma16(short8 a, short8 b, floatx4 c) {
    return __builtin_amdgcn_mfma_f32_16x16x32_bf16(a, b, c, 0, 0, 0);
}

// ---- prep: build per-thread B-fragment streams.
// W1frag (k_h1, 512-thr): [kt*8192 + t*16 + j*8 + ji] = bf16(W1[(7+kt*32+lq*8+ji)*256 + w*32+j*16+lr])
// W2frag (k_tail p1, 256-thr): [kt*8192 + t*32 + jj*8 + ji] = bf16(W2[(kt*32+lq*8+ji)*256 + wv*64+jj*16+lr])
// W3frag (k_tail p2, 256-thr): [kt*4096 + t*16 + j*8 + ji]  = bf16(W3[(kt*32+lq*8+ji)*128 + wv*32+j*16+lr])
__global__ void k_prep(const float* __restrict__ W1, const float* __restrict__ W2,
                       const float* __restrict__ W3, u16* __restrict__ W1frag,
                       u16* __restrict__ W2frag, u16* __restrict__ W3frag) {
    int idx = blockIdx.x * 256 + threadIdx.x;
    if (idx < 524288) {
        int kt = idx >> 13, r = idx & 8191;
        int t = r >> 4, j = (r >> 3) & 1, ji = r & 7;
        int lane = t & 63, w = t >> 6, lr = lane & 15, lq = lane >> 4;
        W1frag[idx] = f2bf(W1[(7 + kt * 32 + lq * 8 + ji) * 256 + w * 32 + j * 16 + lr]);
    } else if (idx < 589824) {
        int i = idx - 524288;
        int kt = i >> 13, r = i & 8191;
        int t = r >> 5, jj = (r >> 3) & 3, ji = r & 7;
        int lane = t & 63, wv = t >> 6, lr = lane & 15, lq = lane >> 4;
        W2frag[i] = f2bf(W2[(kt * 32 + lq * 8 + ji) * 256 + wv * 64 + jj * 16 + lr]);
    } else if (idx < 622592) {
        int i = idx - 589824;
        int kt = i >> 12, r = i & 4095;
        int t = r >> 4, j = (r >> 3) & 1, ji = r & 7;
        int lane = t & 63, wv = t >> 6, lr = lane & 15, lq = lane >> 4;
        W3frag[i] = f2bf(W3[(kt * 32 + lq * 8 + ji) * 128 + wv * 32 + j * 16 + lr]);
    }
}

// ---- kernel 1: h1 = lrelu( [u,norm,proj,dots] @ W1 + b1 )
// 512 threads (8 waves), M=64 x N=256 per block; wave w owns cols w*32..+32.
// Superstep = K=64 (2 MFMA k-tiles) per barrier; 32 barriers total.
// As dots tile: [2][64][64] bf16, row = 128 B = 8x 16B slots, physical slot =
// data slot ^ (row&7). ds_write_b128 (wave w -> slot w of row lane) and
// ds_read_b128 (slot (4kk+lq)^(lr&7)) are both conflict-free (verified:
// SQ_LDS_BANK_CONFLICT 7.5M -> 128K in round 2).
// Register discipline (round-2 spill post-mortem): ONE a[4] set reused for
// kk=0/1, B single-buffered (loads issued at superstep top, hidden under the
// gen VALU block) -> ~32 frag VGPRs instead of 64; no scratch.
__global__ __launch_bounds__(512, 4) void k_h1(
    const float* __restrict__ x, const float* __restrict__ u,
    const float* __restrict__ basis, const float* __restrict__ W1,
    const float* __restrict__ b1, const u16* __restrict__ W1frag,
    u16* __restrict__ h1) {
    __shared__ float xls[6144];       // SoA: X[0..2048) Y[2048..4096) Z[4096..6144)
    __shared__ u16 As[2][64][64];     // 16 KB double-buffered dots tile (swizzled)
    __shared__ float rowsml[64][6];
    __shared__ float colsml[256][6];

    const int t = threadIdx.x;
    const int b = blockIdx.y;
    const int i0 = blockIdx.x * 64;
    const int lane = t & 63, w = t >> 6;
    const int lr = lane & 15, lq = lane >> 4;

    // build SoA copy of x[b] (coalesced read, scalar LDS scatter; one-time)
    {
        const float4* src = (const float4*)(x + b * 6144);
#pragma unroll
        for (int kk = 0; kk < 3; ++kk) {
            int q = t + kk * 512;
            float4 v = src[q];
            float vv[4] = {v.x, v.y, v.z, v.w};
            int e = q * 4;
#pragma unroll
            for (int cc = 0; cc < 4; ++cc) {
                int ee = e + cc;
                xls[(ee % 3) * 2048 + ee / 3] = vv[cc];
            }
        }
    }
    if (t < 256) {
        int c = t;
        float u0 = u[b * 2 + 0], u1 = u[b * 2 + 1];
        colsml[c][0] = b1[c] + u0 * W1[c] + u1 * W1[256 + c];
        colsml[c][1] = W1[512 + c];
        colsml[c][2] = W1[768 + c];
        colsml[c][3] = W1[1024 + c];
        colsml[c][4] = W1[1280 + c];
        colsml[c][5] = W1[1536 + c];
    }
    __syncthreads();
    if (t < 64) {
        float xx = xls[i0 + t], xy = xls[2048 + i0 + t], xz = xls[4096 + i0 + t];
        rowsml[t][0] = sqrtf(xx * xx + xy * xy + xz * xz);
#pragma unroll
        for (int p = 0; p < 4; ++p) {
            const float* bp = basis + (b * 4 + p) * 3;
            rowsml[t][1 + p] = xx * bp[0] + xy * bp[1] + xz * bp[2];
        }
    }
    const float ax = xls[i0 + lane];
    const float ay = xls[2048 + i0 + lane];
    const float az = xls[4096 + i0 + lane];
    const u16* wf = W1frag + t * 16;
    const float4* X4 = (const float4*)xls;  // [0..512) X, [512..1024) Y, [1024..1536) Z

    // swizzled LDS addressing (all loop-invariant)
    char* Asb = (char*)As;
    char* aswp = Asb + lane * 128 + ((w ^ (lane & 7)) << 4);   // write ptr, buf0
    int ro[4];
    {
        int sl = (lq ^ (lr & 7));
#pragma unroll
        for (int i = 0; i < 4; ++i)
            ro[i] = (i * 16 + lr) * 128 + (sl << 4);           // kk=0; kk=1 is ^64
    }

    // generate 8 dots (cols s*64 + w*8 ..+8) for superstep s into As[buf]
    auto gen_store = [&](int s, int buf) {
        int q = s * 16 + w * 2;                   // wave-uniform -> LDS broadcast
        v2f dA, dB, dC, dD;
        {
            float4 a0 = X4[q], a1 = X4[q + 1];
            v2f t0 = {a0.x, a0.y}, t1 = {a0.z, a0.w};
            v2f t2 = {a1.x, a1.y}, t3 = {a1.z, a1.w};
            dA = t0 * ax; dB = t1 * ax; dC = t2 * ax; dD = t3 * ax;
        }
        {
            float4 a0 = X4[512 + q], a1 = X4[513 + q];
            v2f t0 = {a0.x, a0.y}, t1 = {a0.z, a0.w};
            v2f t2 = {a1.x, a1.y}, t3 = {a1.z, a1.w};
            dA += t0 * ay; dB += t1 * ay; dC += t2 * ay; dD += t3 * ay;
        }
        {
            float4 a0 = X4[1024 + q], a1 = X4[1025 + q];
            v2f t0 = {a0.x, a0.y}, t1 = {a0.z, a0.w};
            v2f t2 = {a1.x, a1.y}, t3 = {a1.z, a1.w};
            dA += t0 * az; dB += t1 * az; dC += t2 * az; dD += t3 * az;
        }
        float s0 = __builtin_amdgcn_sqrtf(dA.x);
        float s1 = __builtin_amdgcn_sqrtf(dA.y);
        float s2 = __builtin_amdgcn_sqrtf(dB.x);
        float s3 = __builtin_amdgcn_sqrtf(dB.y);
        float s4 = __builtin_amdgcn_sqrtf(dC.x);
        float s5 = __builtin_amdgcn_sqrtf(dC.y);
        float s6 = __builtin_amdgcn_sqrtf(dD.x);
        float s7 = __builtin_amdgcn_sqrtf(dD.y);
        uint4 dv;
        dv.x = pack2bf(s0, s1); dv.y = pack2bf(s2, s3);
        dv.z = pack2bf(s4, s5); dv.w = pack2bf(s6, s7);
        *(uint4*)(aswp + buf * 8192) = dv;
    };

    floatx4 acc[4][2];
    const floatx4 zero = {0.f, 0.f, 0.f, 0.f};
#pragma unroll
    for (int i = 0; i < 4; ++i)
#pragma unroll
        for (int j = 0; j < 2; ++j) acc[i][j] = zero;

    gen_store(0, 0);
    __syncthreads();

    short8 a[4], bfr[4];
#pragma unroll 2
    for (int s = 0; s < 32; ++s) {
        const int buf = s & 1;
        // B frags for both kk (L2-hot stream; latency hidden under gen VALU)
        const u16* wb = wf + (2 * s) * 8192;
        bfr[0] = *(const short8*)(wb);
        bfr[1] = *(const short8*)(wb + 8);
        bfr[2] = *(const short8*)(wb + 8192);
        bfr[3] = *(const short8*)(wb + 8192 + 8);
        // A kk=0
#pragma unroll
        for (int i = 0; i < 4; ++i)
            a[i] = *(const short8*)(Asb + buf * 8192 + ro[i]);
        // dots for next superstep -> other buffer (read-free this superstep)
        if (s < 31) gen_store(s + 1, buf ^ 1);
#pragma unroll
        for (int i = 0; i < 4; ++i)
#pragma unroll
            for (int j = 0; j < 2; ++j)
                acc[i][j] = mfma16(a[i], bfr[j], acc[i][j]);
        // A kk=1 (same buffer; reads hide under other waves' MFMA issue)
#pragma unroll
        for (int i = 0; i < 4; ++i)
            a[i] = *(const short8*)(Asb + buf * 8192 + (ro[i] ^ 64));
#pragma unroll
        for (int i = 0; i < 4; ++i)
#pragma unroll
            for (int j = 0; j < 2; ++j)
                acc[i][j] = mfma16(a[i], bfr[2 + j], acc[i][j]);
        __syncthreads();
    }

    // epilogue: small features + bias, LeakyReLU, store bf16
    const int c0 = w * 32 + lr, c1 = c0 + 16;
    float c0v[6], c1v[6];
#pragma unroll
    for (int q = 0; q < 6; ++q) { c0v[q] = colsml[c0][q]; c1v[q] = colsml[c1][q]; }
#pragma unroll
    for (int i = 0; i < 4; ++i) {
#pragma unroll
        for (int r = 0; r < 4; ++r) {
            int row = i * 16 + lq * 4 + r;
            float nrm = rowsml[row][0];
            float p0 = rowsml[row][1], p1 = rowsml[row][2];
            float p2 = rowsml[row][3], p3 = rowsml[row][4];
            u16* orow = h1 + (b * 2048 + i0 + row) * 256;
            float v0 = acc[i][0][r] + c0v[0] + nrm * c0v[1] +
                       p0 * c0v[2] + p1 * c0v[3] + p2 * c0v[4] + p3 * c0v[5];
            v0 = v0 > 0.f ? v0 : 0.01f * v0;
            orow[c0] = f2bf(v0);
            float v1 = acc[i][1][r] + c1v[0] + nrm * c1v[1] +
                       p0 * c1v[2] + p1 * c1v[3] + p2 * c1v[4] + p3 * c1v[5];
            v1 = v1 > 0.f ? v1 : 0.01f * v1;
            orow[c1] = f2bf(v1);
        }
    }
}

// ---- fused tail: h2 = lrelu(h1@W2+b2) (regs->LDS), fk = h2@W3+b3, x-reduce.
// Phase 1 is barrier-free: A-frags direct from global h1, B-frags from W2frag stream.
// Final reduce: scaled by 1/2048 (exact pow2) and atomicAdd straight into out.
__global__ __launch_bounds__(256, 2) void k_tail(
    const u16* __restrict__ h1, const u16* __restrict__ W2frag,
    const float* __restrict__ b2, const u16* __restrict__ W3frag,
    const float* __restrict__ b3, const float* __restrict__ x,
    float* __restrict__ out) {
    __shared__ u16 h2s[64][264];    // 33.8 KB
    __shared__ float colb2[256];
    __shared__ float colb3[128];
    __shared__ float xs[64][4];
    __shared__ float red[128][4];

    const int t = threadIdx.x;
    const int m0 = blockIdx.x * 64;
    const int b = m0 >> 11, i0 = m0 & 2047;
    const int lane = t & 63, wv = t >> 6;
    const int lr = lane & 15, lq = lane >> 4;

    colb2[t] = b2[t];
    if (t < 128) colb3[t] = b3[t];
    if (t < 64) {
        const float* xp = x + (b * 2048 + i0 + t) * 3;
        xs[t][0] = xp[0]; xs[t][1] = xp[1]; xs[t][2] = xp[2];
    }

    // ---- phase 1: h2 tile (no barriers, no LDS staging)
    floatx4 acc[4][4];
    const floatx4 zero = {0.f, 0.f, 0.f, 0.f};
#pragma unroll
    for (int i = 0; i < 4; ++i)
#pragma unroll
        for (int j = 0; j < 4; ++j) acc[i][j] = zero;

    const u16* hsrc = h1 + m0 * 256 + lr * 256 + lq * 8;
    const u16* w2s = W2frag + t * 32;
#pragma unroll 2
    for (int kt = 0; kt < 8; ++kt) {
        short8 af[4], bf[4];
#pragma unroll
        for (int i = 0; i < 4; ++i)
            af[i] = *(const short8*)(hsrc + i * 4096 + kt * 32);
#pragma unroll
        for (int j = 0; j < 4; ++j)
            bf[j] = *(const short8*)(w2s + kt * 8192 + j * 8);
#pragma unroll
        for (int i = 0; i < 4; ++i)
#pragma unroll
            for (int j = 0; j < 4; ++j) acc[i][j] = mfma16(af[i], bf[j], acc[i][j]);
    }
#pragma unroll
    for (int i = 0; i < 4; ++i)
#pragma unroll
        for (int r = 0; r < 4; ++r) {
            int row = i * 16 + lq * 4 + r;
#pragma unroll
            for (int j = 0; j < 4; ++j) {
                int col = wv * 64 + j * 16 + lr;
                float v = acc[i][j][r] + colb2[col];
                v = v > 0.f ? v : 0.01f * v;
                h2s[row][col] = f2bf(v);
            }
        }
    __syncthreads();

    // ---- phase 2: fk = h2s @ W3 + b3 (B from W3frag stream), fused x-reduce
    floatx4 acc2[4][2];
#pragma unroll
    for (int i = 0; i < 4; ++i)
#pragma unroll
        for (int j = 0; j < 2; ++j) acc2[i][j] = zero;

    const u16* w3s = W3frag + t * 16;
#pragma unroll 2
    for (int kt = 0; kt < 8; ++kt) {
        short8 af[4], bf[2];
#pragma unroll
        for (int i = 0; i < 4; ++i)
            af[i] = *(const short8*)&h2s[i * 16 + lr][kt * 32 + lq * 8];
#pragma unroll
        for (int j = 0; j < 2; ++j)
            bf[j] = *(const short8*)(w3s + kt * 4096 + j * 8);
#pragma unroll
        for (int i = 0; i < 4; ++i)
#pragma unroll
            for (int j = 0; j < 2; ++j) acc2[i][j] = mfma16(af[i], bf[j], acc2[i][j]);
    }

    float s[2][3];
#pragma unroll
    for (int j = 0; j < 2; ++j) { s[j][0] = 0.f; s[j][1] = 0.f; s[j][2] = 0.f; }
#pragma unroll
    for (int i = 0; i < 4; ++i)
#pragma unroll
        for (int r = 0; r < 4; ++r) {
            int row = i * 16 + lq * 4 + r;
            float x0 = xs[row][0], x1 = xs[row][1], x2 = xs[row][2];
#pragma unroll
            for (int j = 0; j < 2; ++j) {
                int col = wv * 32 + j * 16 + lr;
                float fk = acc2[i][j][r] + colb3[col];
                s[j][0] += fk * x0; s[j][1] += fk * x1; s[j][2] += fk * x2;
            }
        }
#pragma unroll
    for (int j = 0; j < 2; ++j)
#pragma unroll
        for (int d = 0; d < 3; ++d) {
            float v = s[j][d];
            v += __shfl_xor(v, 16);
            v += __shfl_xor(v, 32);
            if (lane < 16) red[wv * 32 + j * 16 + lane][d] = v;  // wave-exclusive cols
        }
    __syncthreads();
    if (t < 128) {
#pragma unroll
        for (int d = 0; d < 3; ++d)
            atomicAdd(&out[(b * 128 + t) * 3 + d], red[t][d] * (1.0f / 2048.0f));
    }
}

extern "C" void kernel_launch(void* const* d_in, const int* in_sizes, int n_in,
                              void* d_out, int out_size, void* d_ws, size_t ws_size,
                              hipStream_t stream) {
    const float* x     = (const float*)d_in[0];
    const float* u     = (const float*)d_in[1];
    const float* basis = (const float*)d_in[2];
    const float* W1    = (const float*)d_in[3];
    const float* b1    = (const float*)d_in[4];
    const float* W2    = (const float*)d_in[5];
    const float* b2    = (const float*)d_in[6];
    const float* W3    = (const float*)d_in[7];
    const float* b3    = (const float*)d_in[8];
    float* out = (float*)d_out;

    char* ws = (char*)d_ws;
    u16*  W1frag = (u16*)ws;                      // 1,048,576 B
    u16*  W2frag = (u16*)(ws + 1048576);          //   131,072 B
    u16*  W3frag = (u16*)(ws + 1179648);          //    65,536 B
    u16*  h1     = (u16*)(ws + 1245184);          // 16,777,216 B

    hipMemsetAsync(out, 0, 24576, stream);
    k_prep<<<2432, 256, 0, stream>>>(W1, W2, W3, W1frag, W2frag, W3frag);
    k_h1<<<dim3(32, 16), 512, 0, stream>>>(x, u, basis, W1, b1, W1frag, h1);
    k_tail<<<512, 256, 0, stream>>>(h1, W2frag, b2, W3frag, b3, x, out);
}